// Round 1
// baseline (955.227 us; speedup 1.0000x reference)
//
#include <hip/hip_runtime.h>
#include <hip/hip_fp16.h>

// Problem constants
#define BB 4
#define SS 2048
#define HH 16
#define DKK 64
#define DMODEL 1024
#define NEGV -1.0e9f

typedef __attribute__((ext_vector_type(8))) _Float16 half8;
typedef __attribute__((ext_vector_type(4))) float floatx4;

#define MFMA16(a, b, c) __builtin_amdgcn_mfma_f32_16x16x32_f16(a, b, c, 0, 0, 0)

// ---------------------------------------------------------------------------
// Projection GEMM: Y = X @ W + bias, X: [8192,1024] f32, W: [1024,1024] f32.
// Output fp16, scattered to attention-friendly layout:
//   vmode==0: out[b][h][s][d]   (Q, K)
//   vmode==1: out[b][h][d][s]   (V transposed, for PV B-operand frags)
// Block: 256 thr (4 waves), tile 64(M)x64(N), BK=64, MFMA 16x16x32 f16.
// ---------------------------------------------------------------------------
__global__ __launch_bounds__(256)
void proj_kernel(const float* __restrict__ X, const float* __restrict__ W,
                 const float* __restrict__ bias, _Float16* __restrict__ out,
                 int vmode)
{
    __shared__ __attribute__((aligned(16))) _Float16 As[64][72]; // [m][k]
    __shared__ __attribute__((aligned(16))) _Float16 Bs[64][72]; // [n][k] (W^T)

    const int tid  = threadIdx.x;
    const int wave = tid >> 6;
    const int lane = tid & 63;
    const int quad = lane >> 4;
    const int l16  = lane & 15;
    const int m0 = blockIdx.y * 64;
    const int n0 = blockIdx.x * 64;

    floatx4 acc[4] = {};

    for (int k0 = 0; k0 < DMODEL; k0 += 64) {
        __syncthreads(); // WAR vs previous iteration's LDS reads
        // Stage A tile (64 rows x 64 k), fp32 -> fp16
        #pragma unroll
        for (int i = 0; i < 4; i++) {
            int idx = tid + i * 256;              // 1024 float4 slots
            int row = idx >> 4;
            int c4  = (idx & 15) << 2;
            float4 v = *(const float4*)(X + (size_t)(m0 + row) * DMODEL + k0 + c4);
            As[row][c4 + 0] = (_Float16)v.x;
            As[row][c4 + 1] = (_Float16)v.y;
            As[row][c4 + 2] = (_Float16)v.z;
            As[row][c4 + 3] = (_Float16)v.w;
        }
        // Stage B tile transposed: W[k0+r][n0+c] -> Bs[c][r]
        #pragma unroll
        for (int i = 0; i < 4; i++) {
            int idx = tid + i * 256;
            int r  = idx >> 4;
            int c4 = (idx & 15) << 2;
            float4 v = *(const float4*)(W + (size_t)(k0 + r) * DMODEL + n0 + c4);
            Bs[c4 + 0][r] = (_Float16)v.x;
            Bs[c4 + 1][r] = (_Float16)v.y;
            Bs[c4 + 2][r] = (_Float16)v.z;
            Bs[c4 + 3][r] = (_Float16)v.w;
        }
        __syncthreads();

        #pragma unroll
        for (int ks = 0; ks < 2; ks++) {
            half8 af = *(const half8*)&As[wave * 16 + l16][ks * 32 + quad * 8];
            #pragma unroll
            for (int nt = 0; nt < 4; nt++) {
                half8 bf = *(const half8*)&Bs[nt * 16 + l16][ks * 32 + quad * 8];
                acc[nt] = MFMA16(af, bf, acc[nt]);
            }
        }
    }

    // Epilogue: C/D layout row = quad*4+r, col = nt*16+l16
    #pragma unroll
    for (int nt = 0; nt < 4; nt++) {
        int col  = n0 + nt * 16 + l16;
        int head = col >> 6;
        int d    = col & 63;
        float bv = bias[col];
        #pragma unroll
        for (int r = 0; r < 4; r++) {
            int row  = m0 + wave * 16 + quad * 4 + r;
            int bidx = row >> 11;          // / 2048
            int s    = row & 2047;
            float vv = acc[nt][r] + bv;
            size_t oi;
            if (vmode == 0)
                oi = (((size_t)bidx * HH + head) * SS + s) * DKK + d;
            else
                oi = (((size_t)bidx * HH + head) * DKK + d) * SS + s;
            out[oi] = (_Float16)vv;
        }
    }
}

// ---------------------------------------------------------------------------
// Flash attention: one block per (b, h, 64-query tile); wave w owns 16 q rows.
// K and V^T frags loaded directly from global (L1/L2 cached across waves).
// P round-trips through per-wave LDS: C-layout write -> A-layout read.
// ---------------------------------------------------------------------------
__global__ __launch_bounds__(256)
void flash_kernel(const _Float16* __restrict__ Qw, const _Float16* __restrict__ Kw,
                  const _Float16* __restrict__ VTw, const int* __restrict__ mask,
                  const float* __restrict__ resid, float* __restrict__ out)
{
    __shared__ __attribute__((aligned(16))) _Float16 Plds[4][16][72];

    const int tid  = threadIdx.x;
    const int wave = tid >> 6;
    const int lane = tid & 63;
    const int quad = lane >> 4;
    const int l16  = lane & 15;

    const int bx = blockIdx.x;
    const int qt = bx & 31;           // 32 q-tiles of 64
    const int h  = (bx >> 5) & 15;
    const int b  = bx >> 9;
    const int qbase = qt * 64 + wave * 16;   // this wave's first q row
    const size_t bh = (size_t)(b * HH + h);

    // Preload Q A-frags: A[m=l16][k=quad*8+j], two K-steps (k0 = 0, 32)
    const _Float16* Qp = Qw + (bh * SS + qbase + l16) * DKK;
    half8 qf[2];
    qf[0] = *(const half8*)(Qp + quad * 8);
    qf[1] = *(const half8*)(Qp + 32 + quad * 8);

    float mrow[4], lrow[4];
    floatx4 oacc[4] = {};
    #pragma unroll
    for (int r = 0; r < 4; r++) { mrow[r] = -3.0e38f; lrow[r] = 0.0f; }

    const _Float16* Kbase = Kw + bh * SS * DKK;
    const _Float16* Vbase = VTw + bh * DKK * SS;
    const int* mk = mask + b * SS;

    for (int kt = 0; kt < SS / 64; kt++) {
        const int kb = kt * 64;

        // ---- scores: 16(q) x 64(keys), 4 N-subtiles x 2 K-steps
        floatx4 sacc[4] = {};
        #pragma unroll
        for (int ks = 0; ks < 2; ks++) {
            #pragma unroll
            for (int nt = 0; nt < 4; nt++) {
                half8 kf = *(const half8*)(Kbase + (size_t)(kb + nt * 16 + l16) * DKK
                                           + ks * 32 + quad * 8);
                sacc[nt] = MFMA16(qf[ks], kf, sacc[nt]);
            }
        }

        // ---- mask + scale (reference: / DK**(-0.5) == * 8)
        float sc[4][4];
        #pragma unroll
        for (int nt = 0; nt < 4; nt++) {
            int mv = mk[kb + nt * 16 + l16];
            #pragma unroll
            for (int r = 0; r < 4; r++)
                sc[nt][r] = mv ? sacc[nt][r] * 8.0f : NEGV;
        }

        // ---- online softmax stats (rows live across the 16 lanes of a quad)
        float mnew[4], al[4];
        #pragma unroll
        for (int r = 0; r < 4; r++) {
            float t = fmaxf(fmaxf(sc[0][r], sc[1][r]), fmaxf(sc[2][r], sc[3][r]));
            #pragma unroll
            for (int off = 1; off < 16; off <<= 1)
                t = fmaxf(t, __shfl_xor(t, off, 64));
            mnew[r] = fmaxf(mrow[r], t);
            al[r]   = __expf(mrow[r] - mnew[r]);
            mrow[r] = mnew[r];
        }
        float p[4][4];
        #pragma unroll
        for (int nt = 0; nt < 4; nt++)
            #pragma unroll
            for (int r = 0; r < 4; r++)
                p[nt][r] = __expf(sc[nt][r] - mnew[r]);
        #pragma unroll
        for (int r = 0; r < 4; r++) {
            float s = p[0][r] + p[1][r] + p[2][r] + p[3][r];
            #pragma unroll
            for (int off = 1; off < 16; off <<= 1)
                s += __shfl_xor(s, off, 64);
            lrow[r] = lrow[r] * al[r] + s;
        }
        #pragma unroll
        for (int dt = 0; dt < 4; dt++)
            #pragma unroll
            for (int r = 0; r < 4; r++)
                oacc[dt][r] *= al[r];

        // ---- P: C-layout -> LDS -> A-layout
        #pragma unroll
        for (int nt = 0; nt < 4; nt++)
            #pragma unroll
            for (int r = 0; r < 4; r++)
                Plds[wave][quad * 4 + r][nt * 16 + l16] = (_Float16)p[nt][r];
        __syncthreads();

        // ---- PV: ctx 16(q) x 64(d); B-frag from V^T rows (contiguous in key)
        #pragma unroll
        for (int ks = 0; ks < 2; ks++) {
            half8 pf = *(const half8*)&Plds[wave][l16][ks * 32 + quad * 8];
            #pragma unroll
            for (int dt = 0; dt < 4; dt++) {
                half8 vf = *(const half8*)(Vbase + (size_t)(dt * 16 + l16) * SS
                                           + kb + ks * 32 + quad * 8);
                oacc[dt] = MFMA16(pf, vf, oacc[dt]);
            }
        }
        __syncthreads();
    }

    // ---- epilogue: out = ctx / l + residual
    #pragma unroll
    for (int dt = 0; dt < 4; dt++) {
        int col = h * DKK + dt * 16 + l16;
        #pragma unroll
        for (int r = 0; r < 4; r++) {
            int row = qbase + quad * 4 + r;
            size_t gi = ((size_t)b * SS + row) * DMODEL + col;
            out[gi] = oacc[dt][r] / lrow[r] + resid[gi];
        }
    }
}

// ---------------------------------------------------------------------------
extern "C" void kernel_launch(void* const* d_in, const int* in_sizes, int n_in,
                              void* d_out, int out_size, void* d_ws, size_t ws_size,
                              hipStream_t stream)
{
    const float* q    = (const float*)d_in[0];
    const float* k    = (const float*)d_in[1];
    const float* v    = (const float*)d_in[2];
    const int*   mask = (const int*)d_in[3];
    const float* wq   = (const float*)d_in[4];
    const float* bq   = (const float*)d_in[5];
    const float* wk   = (const float*)d_in[6];
    const float* bk   = (const float*)d_in[7];
    const float* wv   = (const float*)d_in[8];
    const float* bv   = (const float*)d_in[9];
    float* out = (float*)d_out;

    const size_t TENS = (size_t)BB * SS * HH * DKK;  // 8192*1024
    _Float16* Qws  = (_Float16*)d_ws;
    _Float16* Kws  = Qws + TENS;
    _Float16* VTws = Kws + TENS;

    dim3 pg(DMODEL / 64, (BB * SS) / 64), pb(256);
    hipLaunchKernelGGL(proj_kernel, pg, pb, 0, stream, q, wq, bq, Qws, 0);
    hipLaunchKernelGGL(proj_kernel, pg, pb, 0, stream, k, wk, bk, Kws, 0);
    hipLaunchKernelGGL(proj_kernel, pg, pb, 0, stream, v, wv, bv, VTws, 1);
    hipLaunchKernelGGL(flash_kernel, dim3(BB * HH * (SS / 64)), pb, 0, stream,
                       Qws, Kws, VTws, mask, q, out);
}

// Round 3
// 575.556 us; speedup vs baseline: 1.6597x; 1.6597x over previous
//
#include <hip/hip_runtime.h>
#include <hip/hip_fp16.h>

#define BB 4
#define SS 2048
#define HH 16
#define DKK 64
#define DMODEL 1024

typedef __attribute__((ext_vector_type(8))) _Float16 half8;
typedef __attribute__((ext_vector_type(4))) float floatx4;

#define MFMA16(a, b, c) __builtin_amdgcn_mfma_f32_16x16x32_f16(a, b, c, 0, 0, 0)

// 8 * log2(e): reference scale is *8; we run softmax in exp2 domain
#define SCL2 11.5415603336f

// ---------------- DPP 16-lane row reductions (2-cyc VALU vs ~40-cyc swizzle) ----
template <int CTRL>
__device__ __forceinline__ float dpp_f(float x) {
    int r = __builtin_amdgcn_update_dpp(0, __float_as_int(x), CTRL, 0xf, 0xf, true);
    return __int_as_float(r);
}
__device__ __forceinline__ float row_sum16(float x) {
    x += dpp_f<0xB1>(x);   // quad_perm xor1
    x += dpp_f<0x4E>(x);   // quad_perm xor2
    x += dpp_f<0x124>(x);  // row_ror:4
    x += dpp_f<0x128>(x);  // row_ror:8
    return x;
}
__device__ __forceinline__ float row_max16(float x) {
    x = fmaxf(x, dpp_f<0xB1>(x));
    x = fmaxf(x, dpp_f<0x4E>(x));
    x = fmaxf(x, dpp_f<0x124>(x));
    x = fmaxf(x, dpp_f<0x128>(x));
    return x;
}

// ---------------- async global->LDS, 16B per lane ------------------------------
__device__ __forceinline__ void gload_lds16(const _Float16* g, _Float16* l) {
    __builtin_amdgcn_global_load_lds(
        (const __attribute__((address_space(1))) void*)g,
        (__attribute__((address_space(3))) void*)l, 16, 0, 0);
}

// ---------------- fp32 -> fp16 convert of X (q,k,v), k-unit XOR swizzle --------
// element (m,k) stored at column k ^ ((m&7)<<3) so LDS frag reads are bank-free
__global__ __launch_bounds__(256)
void convert_x(const float* __restrict__ q, const float* __restrict__ k,
               const float* __restrict__ v, _Float16* __restrict__ xq,
               _Float16* __restrict__ xk, _Float16* __restrict__ xv)
{
    int z = blockIdx.y;
    const float* src = (z == 0) ? q : (z == 1) ? k : v;
    _Float16* dst = (z == 0) ? xq : (z == 1) ? xk : xv;
    size_t base = ((size_t)blockIdx.x * 256 + threadIdx.x) * 8;
    int m = (int)(base >> 10);
    int kk = (int)(base & 1023);
    float4 a = *(const float4*)(src + base);
    float4 b = *(const float4*)(src + base + 4);
    half8 h;
    h[0] = (_Float16)a.x; h[1] = (_Float16)a.y; h[2] = (_Float16)a.z; h[3] = (_Float16)a.w;
    h[4] = (_Float16)b.x; h[5] = (_Float16)b.y; h[6] = (_Float16)b.z; h[7] = (_Float16)b.w;
    int kd = kk ^ ((m & 7) << 3);
    *(half8*)(dst + ((size_t)m << 10) + kd) = h;
}

// ---------------- W[k][n] -> WT[n][k] fp16, same k-unit swizzle by (n&7) -------
__global__ __launch_bounds__(256)
void convert_wt(const float* __restrict__ wq, const float* __restrict__ wk,
                const float* __restrict__ wv, _Float16* __restrict__ tq,
                _Float16* __restrict__ tk, _Float16* __restrict__ tv)
{
    __shared__ __attribute__((aligned(16))) _Float16 T[64][72]; // [n_loc][k_loc]
    int z = blockIdx.y;
    const float* W = (z == 0) ? wq : (z == 1) ? wk : wv;
    _Float16* WT = (z == 0) ? tq : (z == 1) ? tk : tv;
    int kt = (blockIdx.x >> 4) << 6;
    int nt = (blockIdx.x & 15) << 6;
    int tid = threadIdx.x;
    #pragma unroll
    for (int p = 0; p < 4; p++) {
        int lin = tid + p * 256;           // 1024 float4 slots
        int row = lin >> 4;                // k_loc
        int c4 = (lin & 15) << 2;          // n_loc
        float4 vv = *(const float4*)(W + (size_t)(kt + row) * DMODEL + nt + c4);
        T[c4 + 0][row] = (_Float16)vv.x;
        T[c4 + 1][row] = (_Float16)vv.y;
        T[c4 + 2][row] = (_Float16)vv.z;
        T[c4 + 3][row] = (_Float16)vv.w;
    }
    __syncthreads();
    #pragma unroll
    for (int p = 0; p < 2; p++) {
        int lin = tid + p * 256;           // 512 half8 slots
        int nl = lin >> 3;
        int u = lin & 7;
        half8 h = *(const half8*)&T[nl][u * 8];
        int n = nt + nl;
        int kd = kt + ((u ^ (n & 7)) << 3);
        *(half8*)(WT + (size_t)n * DMODEL + kd) = h;
    }
}

// ---------------- 128x128 projection GEMM, fp16 in, global_load_lds staging ----
// VMODE 0: out[b][h][s][d] (Q,K).  VMODE 1: operands swapped -> Y^T, out[b][h][d][s].
template <int VMODE>
__global__ __launch_bounds__(256)
void proj128(const _Float16* __restrict__ X, const _Float16* __restrict__ WT,
             const float* __restrict__ bias, _Float16* __restrict__ out)
{
    __shared__ __attribute__((aligned(16))) _Float16 As[128 * 64];
    __shared__ __attribute__((aligned(16))) _Float16 Bs[128 * 64];
    const int tid = threadIdx.x;
    const int wave = tid >> 6, lane = tid & 63, quad = lane >> 4, l16 = lane & 15;
    const int wm = wave >> 1, wn = wave & 1;
    const int m0 = (blockIdx.x >> 3) << 7;
    const int n0 = (blockIdx.x & 7) << 7;
    const int lrow = lane >> 3;            // 0..7 (row within 8-row group)
    const int lcol = (lane & 7) << 3;      // halves

    floatx4 acc[4][4] = {};

    for (int k0 = 0; k0 < DMODEL; k0 += 64) {
        __syncthreads();
        #pragma unroll
        for (int c = 0; c < 4; c++) {
            int row = c * 32 + wave * 8;
            gload_lds16(X + (size_t)(m0 + row + lrow) * DMODEL + k0 + lcol,
                        As + (size_t)row * 64);
            gload_lds16(WT + (size_t)(n0 + row + lrow) * DMODEL + k0 + lcol,
                        Bs + (size_t)row * 64);
        }
        __syncthreads();
        #pragma unroll
        for (int ks = 0; ks < 2; ks++) {
            int ccol = ((ks * 4 + quad) ^ (l16 & 7)) << 3;
            half8 af[4], bf[4];
            #pragma unroll
            for (int i = 0; i < 4; i++)
                af[i] = *(const half8*)(As + (wm * 64 + i * 16 + l16) * 64 + ccol);
            #pragma unroll
            for (int jj = 0; jj < 4; jj++)
                bf[jj] = *(const half8*)(Bs + (wn * 64 + jj * 16 + l16) * 64 + ccol);
            #pragma unroll
            for (int i = 0; i < 4; i++)
                #pragma unroll
                for (int jj = 0; jj < 4; jj++)
                    acc[i][jj] = VMODE ? MFMA16(bf[jj], af[i], acc[i][jj])
                                       : MFMA16(af[i], bf[jj], acc[i][jj]);
        }
    }

    if (VMODE == 0) {
        #pragma unroll
        for (int jj = 0; jj < 4; jj++) {
            int ng = n0 + wn * 64 + jj * 16 + l16;
            int h = ng >> 6, d = ng & 63;
            float bv = bias[ng];
            #pragma unroll
            for (int i = 0; i < 4; i++)
                #pragma unroll
                for (int r = 0; r < 4; r++) {
                    int mg = m0 + wm * 64 + i * 16 + quad * 4 + r;
                    int bb = mg >> 11, s = mg & 2047;
                    out[(((size_t)bb * HH + h) * SS + s) * DKK + d] =
                        (_Float16)(acc[i][jj][r] + bv);
                }
        }
    } else {
        #pragma unroll
        for (int jj = 0; jj < 4; jj++)
            #pragma unroll
            for (int r = 0; r < 4; r++) {
                int ng = n0 + wn * 64 + jj * 16 + quad * 4 + r;
                int h = ng >> 6, d = ng & 63;
                float bv = bias[ng];
                #pragma unroll
                for (int i = 0; i < 4; i++) {
                    int mg = m0 + wm * 64 + i * 16 + l16;
                    int bb = mg >> 11, s = mg & 2047;
                    out[(((size_t)bb * HH + h) * DKK + d) * SS + s] =
                        (_Float16)(acc[i][jj][r] + bv);
                }
            }
    }
}

// ---------------- flash attention: 4 waves x 32 q rows, NO barriers ------------
__global__ __launch_bounds__(256)
void flash2(const _Float16* __restrict__ Qw, const _Float16* __restrict__ Kw,
            const _Float16* __restrict__ VTw, const int* __restrict__ mask,
            const float* __restrict__ resid, float* __restrict__ out)
{
    __shared__ __attribute__((aligned(16))) _Float16 Plds[4][2][16][72]; // wave-private

    const int tid = threadIdx.x;
    const int wave = tid >> 6, lane = tid & 63, quad = lane >> 4, l16 = lane & 15;
    // XCD swizzle: all 16 q-tiles of one (b,h) land on one XCD (blockIdx % 8)
    const int bx = blockIdx.x;
    const int xcd = bx & 7;
    const int jj = bx >> 3;
    const int bh = ((jj >> 4) << 3) | xcd;
    const int qt = jj & 15;
    const int b = bh >> 4;
    const int h = bh & 15;
    const int qbase = qt * 128 + wave * 32;

    half8 qf[2][2];
    #pragma unroll
    for (int mt = 0; mt < 2; mt++) {
        const _Float16* Qp = Qw + ((size_t)bh * SS + qbase + mt * 16 + l16) * DKK;
        qf[mt][0] = *(const half8*)(Qp + quad * 8);
        qf[mt][1] = *(const half8*)(Qp + 32 + quad * 8);
    }
    float mrow[2][4], lrow[2][4];
    floatx4 oacc[2][4] = {};
    #pragma unroll
    for (int mt = 0; mt < 2; mt++)
        #pragma unroll
        for (int r = 0; r < 4; r++) { mrow[mt][r] = -3.0e38f; lrow[mt][r] = 0.f; }

    const _Float16* Kbase = Kw + (size_t)bh * SS * DKK;
    const _Float16* Vbase = VTw + (size_t)bh * DKK * SS;
    const int* mk = mask + b * SS;

    for (int kt = 0; kt < SS / 64; kt++) {
        const int kb = kt * 64;

        floatx4 sacc[2][4] = {};
        #pragma unroll
        for (int ks = 0; ks < 2; ks++)
            #pragma unroll
            for (int nt = 0; nt < 4; nt++) {
                half8 kf = *(const half8*)(Kbase + (size_t)(kb + nt * 16 + l16) * DKK
                                           + ks * 32 + quad * 8);
                sacc[0][nt] = MFMA16(qf[0][ks], kf, sacc[0][nt]);
                sacc[1][nt] = MFMA16(qf[1][ks], kf, sacc[1][nt]);
            }

        float mbias[4];
        #pragma unroll
        for (int nt = 0; nt < 4; nt++)
            mbias[nt] = mk[kb + nt * 16 + l16] ? 0.f : -1.0e9f;

        #pragma unroll
        for (int mt = 0; mt < 2; mt++) {
            float sc[4][4];
            #pragma unroll
            for (int nt = 0; nt < 4; nt++)
                #pragma unroll
                for (int r = 0; r < 4; r++)
                    sc[nt][r] = fmaf(sacc[mt][nt][r], SCL2, mbias[nt]);
            #pragma unroll
            for (int r = 0; r < 4; r++) {
                float t = fmaxf(fmaxf(sc[0][r], sc[1][r]), fmaxf(sc[2][r], sc[3][r]));
                t = row_max16(t);
                float mn = fmaxf(mrow[mt][r], t);
                float al = exp2f(mrow[mt][r] - mn);
                mrow[mt][r] = mn;
                float psum = 0.f;
                #pragma unroll
                for (int nt = 0; nt < 4; nt++) {
                    float pv = exp2f(sc[nt][r] - mn);
                    sc[nt][r] = pv;
                    psum += pv;
                }
                psum = row_sum16(psum);
                lrow[mt][r] = lrow[mt][r] * al + psum;
                #pragma unroll
                for (int dt = 0; dt < 4; dt++)
                    oacc[mt][dt][r] *= al;
                #pragma unroll
                for (int nt = 0; nt < 4; nt++)
                    Plds[wave][mt][quad * 4 + r][nt * 16 + l16] = (_Float16)sc[nt][r];
            }
        }

        #pragma unroll
        for (int ks = 0; ks < 2; ks++) {
            half8 pf0 = *(const half8*)&Plds[wave][0][l16][ks * 32 + quad * 8];
            half8 pf1 = *(const half8*)&Plds[wave][1][l16][ks * 32 + quad * 8];
            #pragma unroll
            for (int dt = 0; dt < 4; dt++) {
                half8 vf = *(const half8*)(Vbase + (size_t)(dt * 16 + l16) * SS
                                           + kb + ks * 32 + quad * 8);
                oacc[0][dt] = MFMA16(pf0, vf, oacc[0][dt]);
                oacc[1][dt] = MFMA16(pf1, vf, oacc[1][dt]);
            }
        }
    }

    #pragma unroll
    for (int mt = 0; mt < 2; mt++) {
        float rl[4];
        #pragma unroll
        for (int r = 0; r < 4; r++) rl[r] = 1.0f / lrow[mt][r];
        #pragma unroll
        for (int dt = 0; dt < 4; dt++) {
            int col = h * DKK + dt * 16 + l16;
            #pragma unroll
            for (int r = 0; r < 4; r++) {
                int row = qbase + mt * 16 + quad * 4 + r;
                size_t gi = ((size_t)b * SS + row) * DMODEL + col;
                out[gi] = oacc[mt][dt][r] * rl[r] + resid[gi];
            }
        }
    }
}

// ---------------------------------------------------------------------------
extern "C" void kernel_launch(void* const* d_in, const int* in_sizes, int n_in,
                              void* d_out, int out_size, void* d_ws, size_t ws_size,
                              hipStream_t stream)
{
    const float* q    = (const float*)d_in[0];
    const float* k    = (const float*)d_in[1];
    const float* v    = (const float*)d_in[2];
    const int*   mask = (const int*)d_in[3];
    const float* wq   = (const float*)d_in[4];
    const float* bq   = (const float*)d_in[5];
    const float* wk   = (const float*)d_in[6];
    const float* bk   = (const float*)d_in[7];
    const float* wv   = (const float*)d_in[8];
    const float* bv   = (const float*)d_in[9];
    float* out = (float*)d_out;

    const size_t TENS = (size_t)BB * SS * HH * DKK;   // 8388608 halves
    const size_t WSZ  = (size_t)DMODEL * DMODEL;      // 1048576 halves
    _Float16* base = (_Float16*)d_ws;

    _Float16 *Xq, *Xk, *Xv, *Qh, *Kh, *VTh, *WTq;
    if (ws_size >= (6 * TENS + 3 * WSZ) * sizeof(_Float16)) {
        // plenty of workspace: no aliasing
        Xq = base;            Xk = base + TENS;     Xv = base + 2 * TENS;
        Qh = base + 3 * TENS; Kh = base + 4 * TENS; VTh = base + 5 * TENS;
        WTq = base + 6 * TENS;
    } else {
        // stream-ordered aliasing: K reuses Xq's slot, V^T reuses Xk's slot
        Xq = base;            Xk = base + TENS;     Xv = base + 2 * TENS;
        Qh = base + 3 * TENS; Kh = Xq;              VTh = Xk;
        WTq = base + 4 * TENS;
    }
    _Float16* WTk = WTq + WSZ;
    _Float16* WTv = WTk + WSZ;

    hipLaunchKernelGGL(convert_x, dim3(4096, 3), dim3(256), 0, stream, q, k, v, Xq, Xk, Xv);
    hipLaunchKernelGGL(convert_wt, dim3(256, 3), dim3(256), 0, stream, wq, wk, wv, WTq, WTk, WTv);
    hipLaunchKernelGGL((proj128<0>), dim3(512), dim3(256), 0, stream, Xq, WTq, bq, Qh);
    hipLaunchKernelGGL((proj128<0>), dim3(512), dim3(256), 0, stream, Xk, WTk, bk, Kh);
    hipLaunchKernelGGL((proj128<1>), dim3(512), dim3(256), 0, stream, Xv, WTv, bv, VTh);
    hipLaunchKernelGGL(flash2, dim3(BB * HH * (SS / 128)), dim3(256), 0, stream,
                       Qh, Kh, VTh, mask, q, out);
}

// Round 5
// 477.710 us; speedup vs baseline: 1.9996x; 1.2048x over previous
//
#include <hip/hip_runtime.h>
#include <hip/hip_fp16.h>

#define BB 4
#define SS 2048
#define HH 16
#define DKK 64
#define DMODEL 1024

typedef __attribute__((ext_vector_type(8))) _Float16 half8;
typedef __attribute__((ext_vector_type(2))) __fp16 fp16x2;
typedef __attribute__((ext_vector_type(4))) float floatx4;

#define MFMA16(a, b, c) __builtin_amdgcn_mfma_f32_16x16x32_f16(a, b, c, 0, 0, 0)

// 8 * log2(e): reference scale is *8; softmax runs in exp2 domain
#define SCL2 11.5415603336f

// ---------------- async global->LDS, 16B per lane ------------------------------
__device__ __forceinline__ void gload_lds16(const _Float16* g, _Float16* l) {
    __builtin_amdgcn_global_load_lds(
        (const __attribute__((address_space(1))) void*)g,
        (__attribute__((address_space(3))) void*)l, 16, 0, 0);
}

// ---------------- fp32 -> fp16 convert of X (q,k,v), k-unit XOR swizzle --------
__global__ __launch_bounds__(256)
void convert_x(const float* __restrict__ q, const float* __restrict__ k,
               const float* __restrict__ v, _Float16* __restrict__ xq,
               _Float16* __restrict__ xk, _Float16* __restrict__ xv)
{
    int z = blockIdx.y;
    const float* src = (z == 0) ? q : (z == 1) ? k : v;
    _Float16* dst = (z == 0) ? xq : (z == 1) ? xk : xv;
    size_t base = ((size_t)blockIdx.x * 256 + threadIdx.x) * 8;
    int m = (int)(base >> 10);
    int kk = (int)(base & 1023);
    float4 a = *(const float4*)(src + base);
    float4 b = *(const float4*)(src + base + 4);
    half8 h;
    h[0] = (_Float16)a.x; h[1] = (_Float16)a.y; h[2] = (_Float16)a.z; h[3] = (_Float16)a.w;
    h[4] = (_Float16)b.x; h[5] = (_Float16)b.y; h[6] = (_Float16)b.z; h[7] = (_Float16)b.w;
    int kd = kk ^ ((m & 7) << 3);
    *(half8*)(dst + ((size_t)m << 10) + kd) = h;
}

// ---------------- W[k][n] -> WT[n][k] fp16, same k-unit swizzle by (n&7) -------
__global__ __launch_bounds__(256)
void convert_wt(const float* __restrict__ wq, const float* __restrict__ wk,
                const float* __restrict__ wv, _Float16* __restrict__ tq,
                _Float16* __restrict__ tk, _Float16* __restrict__ tv)
{
    __shared__ __attribute__((aligned(16))) _Float16 T[64][72];
    int z = blockIdx.y;
    const float* W = (z == 0) ? wq : (z == 1) ? wk : wv;
    _Float16* WT = (z == 0) ? tq : (z == 1) ? tk : tv;
    int kt = (blockIdx.x >> 4) << 6;
    int nt = (blockIdx.x & 15) << 6;
    int tid = threadIdx.x;
    #pragma unroll
    for (int p = 0; p < 4; p++) {
        int lin = tid + p * 256;
        int row = lin >> 4;
        int c4 = (lin & 15) << 2;
        float4 vv = *(const float4*)(W + (size_t)(kt + row) * DMODEL + nt + c4);
        T[c4 + 0][row] = (_Float16)vv.x;
        T[c4 + 1][row] = (_Float16)vv.y;
        T[c4 + 2][row] = (_Float16)vv.z;
        T[c4 + 3][row] = (_Float16)vv.w;
    }
    __syncthreads();
    #pragma unroll
    for (int p = 0; p < 2; p++) {
        int lin = tid + p * 256;
        int nl = lin >> 3;
        int u = lin & 7;
        half8 h = *(const half8*)&T[nl][u * 8];
        int n = nt + nl;
        int kd = kt + ((u ^ (n & 7)) << 3);
        *(half8*)(WT + (size_t)n * DMODEL + kd) = h;
    }
}

// ---------------- 128x128 projection GEMM body ---------------------------------
template <int VMODE>
__device__ __forceinline__
void proj_body(const _Float16* __restrict__ X, const _Float16* __restrict__ WT,
               const float* __restrict__ bias, _Float16* __restrict__ out,
               int bidx)
{
    __shared__ __attribute__((aligned(16))) _Float16 As[128 * 64];
    __shared__ __attribute__((aligned(16))) _Float16 Bs[128 * 64];
    const int tid = threadIdx.x;
    const int wave = tid >> 6, lane = tid & 63, quad = lane >> 4, l16 = lane & 15;
    const int wm = wave >> 1, wn = wave & 1;
    const int m0 = (bidx >> 3) << 7;
    const int n0 = (bidx & 7) << 7;
    const int lrow = lane >> 3;
    const int lcol = (lane & 7) << 3;

    floatx4 acc[4][4] = {};

    for (int k0 = 0; k0 < DMODEL; k0 += 64) {
        __syncthreads();
        #pragma unroll
        for (int c = 0; c < 4; c++) {
            int row = c * 32 + wave * 8;
            gload_lds16(X + (size_t)(m0 + row + lrow) * DMODEL + k0 + lcol,
                        As + (size_t)row * 64);
            gload_lds16(WT + (size_t)(n0 + row + lrow) * DMODEL + k0 + lcol,
                        Bs + (size_t)row * 64);
        }
        __syncthreads();
        #pragma unroll
        for (int ks = 0; ks < 2; ks++) {
            int ccol = ((ks * 4 + quad) ^ (l16 & 7)) << 3;
            half8 af[4], bf[4];
            #pragma unroll
            for (int i = 0; i < 4; i++)
                af[i] = *(const half8*)(As + (wm * 64 + i * 16 + l16) * 64 + ccol);
            #pragma unroll
            for (int j = 0; j < 4; j++)
                bf[j] = *(const half8*)(Bs + (wn * 64 + j * 16 + l16) * 64 + ccol);
            #pragma unroll
            for (int i = 0; i < 4; i++)
                #pragma unroll
                for (int j = 0; j < 4; j++)
                    acc[i][j] = VMODE ? MFMA16(bf[j], af[i], acc[i][j])
                                      : MFMA16(af[i], bf[j], acc[i][j]);
        }
    }

    if (VMODE == 0) {
        #pragma unroll
        for (int j = 0; j < 4; j++) {
            int ng = n0 + wn * 64 + j * 16 + l16;
            int h = ng >> 6, d = ng & 63;
            float bv = bias[ng];
            #pragma unroll
            for (int i = 0; i < 4; i++)
                #pragma unroll
                for (int r = 0; r < 4; r++) {
                    int mg = m0 + wm * 64 + i * 16 + quad * 4 + r;
                    int bb = mg >> 11, s = mg & 2047;
                    out[(((size_t)bb * HH + h) * SS + s) * DKK + d] =
                        (_Float16)(acc[i][j][r] + bv);
                }
        }
    } else {
        #pragma unroll
        for (int j = 0; j < 4; j++)
            #pragma unroll
            for (int r = 0; r < 4; r++) {
                int ng = n0 + wn * 64 + j * 16 + quad * 4 + r;
                int h = ng >> 6, d = ng & 63;
                float bv = bias[ng];
                #pragma unroll
                for (int i = 0; i < 4; i++) {
                    int mg = m0 + wm * 64 + i * 16 + l16;
                    int bb = mg >> 11, s = mg & 2047;
                    out[(((size_t)bb * HH + h) * DKK + d) * SS + s] =
                        (_Float16)(acc[i][j][r] + bv);
                }
            }
    }
}

template <int VMODE>
__global__ __launch_bounds__(256)
void proj128(const _Float16* __restrict__ X, const _Float16* __restrict__ WT,
             const float* __restrict__ bias, _Float16* __restrict__ out)
{
    proj_body<VMODE>(X, WT, bias, out, blockIdx.x);
}

// merged Q+K projection (no aliasing between its inputs/outputs required)
__global__ __launch_bounds__(256)
void proj128qk(const _Float16* __restrict__ X0, const _Float16* __restrict__ X1,
               const _Float16* __restrict__ WT0, const _Float16* __restrict__ WT1,
               const float* __restrict__ b0, const float* __restrict__ b1,
               _Float16* __restrict__ o0, _Float16* __restrict__ o1)
{
    if (blockIdx.y == 0) proj_body<0>(X0, WT0, b0, o0, blockIdx.x);
    else                 proj_body<0>(X1, WT1, b1, o1, blockIdx.x);
}

// ---------------- flash attention v3: transposed-scores softmax ----------------
// S^T = MFMA(kf, qf): col=l16=q  -> per-row softmax state is lane-uniform.
// O accumulated as O^T = MFMA(vf, pf): col=l16=q -> alpha scale lane-uniform,
// epilogue is float4. P transpose via packed ds_write_b32 -> ds_read_b128.
__global__ __launch_bounds__(256)
void flash3(const _Float16* __restrict__ Qw, const _Float16* __restrict__ Kw,
            const _Float16* __restrict__ VTw, const int* __restrict__ mask,
            const float* __restrict__ resid, float* __restrict__ out)
{
    __shared__ float Bias[SS];                                            // 8 KB
    __shared__ __attribute__((aligned(16))) _Float16 Plds[4][2][16][72];  // 18 KB

    const int tid = threadIdx.x;
    const int wave = tid >> 6, lane = tid & 63, quad = lane >> 4, l16 = lane & 15;
    const int bx = blockIdx.x;
    const int xcd = bx & 7;
    const int jj = bx >> 3;
    const int bh = ((jj >> 4) << 3) | xcd;   // all 16 q-tiles of a bh on one XCD
    const int qt = jj & 15;
    const int b = bh >> 4;
    const int h = bh & 15;
    const int qbase = qt * 128 + wave * 32;

    // stage mask -> fp32 additive bias (exp2 domain; -1e9 kills)
    const int* mk = mask + b * SS;
    for (int i = tid; i < SS; i += 256)
        Bias[i] = mk[i] ? 0.f : -1.0e9f;
    __syncthreads();

    // Q B-frags: n=q=l16, k=dk
    half8 qf[2][2];
    #pragma unroll
    for (int mt = 0; mt < 2; mt++) {
        const _Float16* Qp = Qw + ((size_t)bh * SS + qbase + mt * 16 + l16) * DKK;
        qf[mt][0] = *(const half8*)(Qp + quad * 8);
        qf[mt][1] = *(const half8*)(Qp + 32 + quad * 8);
    }

    float mrow[2] = {-3.0e38f, -3.0e38f};
    float lrow[2] = {0.f, 0.f};
    floatx4 oacc[2][4] = {};   // O^T: [mt][dt]; col=l16=q, row=quad*4+r=d-local

    const _Float16* Kbase = Kw + (size_t)bh * SS * DKK;
    const _Float16* Vbase = VTw + (size_t)bh * DKK * SS;

    for (int kt = 0; kt < SS / 64; kt++) {
        const int kb = kt * 64;

        // K A-frags: m=key-local=l16, k=dk
        half8 kf[2][4];
        #pragma unroll
        for (int ks = 0; ks < 2; ks++)
            #pragma unroll
            for (int k2 = 0; k2 < 4; k2++)
                kf[ks][k2] = *(const half8*)(Kbase
                    + (size_t)(kb + k2 * 16 + l16) * DKK + ks * 32 + quad * 8);

        // S^T: D[m=key][n=q]
        floatx4 sacc[2][4] = {};
        #pragma unroll
        for (int mt = 0; mt < 2; mt++)
            #pragma unroll
            for (int ks = 0; ks < 2; ks++)
                #pragma unroll
                for (int k2 = 0; k2 < 4; k2++)
                    sacc[mt][k2] = MFMA16(kf[ks][k2], qf[mt][ks], sacc[mt][k2]);

        // V^T A-frags (issue early; consumed after softmax)
        half8 vf[2][4];
        #pragma unroll
        for (int ks = 0; ks < 2; ks++)
            #pragma unroll
            for (int dt = 0; dt < 4; dt++)
                vf[ks][dt] = *(const half8*)(Vbase
                    + (size_t)(dt * 16 + l16) * SS + kb + ks * 32 + quad * 8);

        // bias for keys kb + k2*16 + quad*4 + r (LDS broadcast across l16)
        float4 bs[4];
        #pragma unroll
        for (int k2 = 0; k2 < 4; k2++)
            bs[k2] = *(const float4*)&Bias[kb + k2 * 16 + quad * 4];

        #pragma unroll
        for (int mt = 0; mt < 2; mt++) {
            float p[4][4];
            #pragma unroll
            for (int k2 = 0; k2 < 4; k2++) {
                const float* bp = (const float*)&bs[k2];
                #pragma unroll
                for (int r = 0; r < 4; r++)
                    p[k2][r] = fmaf(sacc[mt][k2][r], SCL2, bp[r]);
            }
            // row max: 15 in-lane + cross-quad (lanes ^16, ^32)
            float t = p[0][0];
            #pragma unroll
            for (int k2 = 0; k2 < 4; k2++)
                #pragma unroll
                for (int r = 0; r < 4; r++)
                    t = fmaxf(t, p[k2][r]);
            t = fmaxf(t, __shfl_xor(t, 16, 64));
            t = fmaxf(t, __shfl_xor(t, 32, 64));
            float mn = fmaxf(mrow[mt], t);
            float al = exp2f(mrow[mt] - mn);
            mrow[mt] = mn;

            float ps = 0.f;
            #pragma unroll
            for (int k2 = 0; k2 < 4; k2++)
                #pragma unroll
                for (int r = 0; r < 4; r++) {
                    float pv = exp2f(p[k2][r] - mn);
                    p[k2][r] = pv;
                    ps += pv;
                }
            ps += __shfl_xor(ps, 16, 64);
            ps += __shfl_xor(ps, 32, 64);
            lrow[mt] = lrow[mt] * al + ps;

            // packed P store: row q=l16, col key-local
            #pragma unroll
            for (int k2 = 0; k2 < 4; k2++) {
                fp16x2 pa = __builtin_amdgcn_cvt_pkrtz(p[k2][0], p[k2][1]);
                fp16x2 pb = __builtin_amdgcn_cvt_pkrtz(p[k2][2], p[k2][3]);
                *(fp16x2*)&Plds[wave][mt][l16][k2 * 16 + quad * 4]     = pa;
                *(fp16x2*)&Plds[wave][mt][l16][k2 * 16 + quad * 4 + 2] = pb;
            }
            // alpha rescale (lane-uniform al)
            #pragma unroll
            for (int dt = 0; dt < 4; dt++)
                oacc[mt][dt] *= al;

            // PV: O^T += V^T x P^T  (A=vf m=d, B=pf n=q)
            #pragma unroll
            for (int ks = 0; ks < 2; ks++) {
                half8 pf = *(const half8*)&Plds[wave][mt][l16][ks * 32 + quad * 8];
                #pragma unroll
                for (int dt = 0; dt < 4; dt++)
                    oacc[mt][dt] = MFMA16(vf[ks][dt], pf, oacc[mt][dt]);
            }
        }
    }

    // epilogue: float4 loads/stores; rl lane-uniform
    #pragma unroll
    for (int mt = 0; mt < 2; mt++) {
        float rl = 1.0f / lrow[mt];
        int s = qbase + mt * 16 + l16;
        size_t rowoff = ((size_t)b * SS + s) * DMODEL + h * DKK;
        #pragma unroll
        for (int dt = 0; dt < 4; dt++) {
            size_t gi = rowoff + dt * 16 + quad * 4;
            float4 rv = *(const float4*)&resid[gi];
            float4 ov;
            ov.x = oacc[mt][dt][0] * rl + rv.x;
            ov.y = oacc[mt][dt][1] * rl + rv.y;
            ov.z = oacc[mt][dt][2] * rl + rv.z;
            ov.w = oacc[mt][dt][3] * rl + rv.w;
            *(float4*)&out[gi] = ov;
        }
    }
}

// ---------------------------------------------------------------------------
extern "C" void kernel_launch(void* const* d_in, const int* in_sizes, int n_in,
                              void* d_out, int out_size, void* d_ws, size_t ws_size,
                              hipStream_t stream)
{
    const float* q    = (const float*)d_in[0];
    const float* k    = (const float*)d_in[1];
    const float* v    = (const float*)d_in[2];
    const int*   mask = (const int*)d_in[3];
    const float* wq   = (const float*)d_in[4];
    const float* bq   = (const float*)d_in[5];
    const float* wk   = (const float*)d_in[6];
    const float* bk   = (const float*)d_in[7];
    const float* wv   = (const float*)d_in[8];
    const float* bv   = (const float*)d_in[9];
    float* out = (float*)d_out;

    const size_t TENS = (size_t)BB * SS * HH * DKK;   // 8388608 halves
    const size_t WSZ  = (size_t)DMODEL * DMODEL;      // 1048576 halves
    _Float16* base = (_Float16*)d_ws;

    bool big = ws_size >= (6 * TENS + 3 * WSZ) * sizeof(_Float16);
    _Float16 *Xq, *Xk, *Xv, *Qh, *Kh, *VTh, *WTq;
    if (big) {
        Xq = base;            Xk = base + TENS;     Xv = base + 2 * TENS;
        Qh = base + 3 * TENS; Kh = base + 4 * TENS; VTh = base + 5 * TENS;
        WTq = base + 6 * TENS;
    } else {
        // stream-ordered aliasing: Kh reuses Xq's slot, VTh reuses Xk's slot
        Xq = base;            Xk = base + TENS;     Xv = base + 2 * TENS;
        Qh = base + 3 * TENS; Kh = Xq;              VTh = Xk;
        WTq = base + 4 * TENS;
    }
    _Float16* WTk = WTq + WSZ;
    _Float16* WTv = WTk + WSZ;

    hipLaunchKernelGGL(convert_x, dim3(4096, 3), dim3(256), 0, stream, q, k, v, Xq, Xk, Xv);
    hipLaunchKernelGGL(convert_wt, dim3(256, 3), dim3(256), 0, stream, wq, wk, wv, WTq, WTk, WTv);
    if (big) {
        hipLaunchKernelGGL(proj128qk, dim3(512, 2), dim3(256), 0, stream,
                           Xq, Xk, WTq, WTk, bq, bk, Qh, Kh);
        hipLaunchKernelGGL((proj128<1>), dim3(512), dim3(256), 0, stream, Xv, WTv, bv, VTh);
    } else {
        hipLaunchKernelGGL((proj128<0>), dim3(512), dim3(256), 0, stream, Xq, WTq, bq, Qh);
        hipLaunchKernelGGL((proj128<0>), dim3(512), dim3(256), 0, stream, Xk, WTk, bk, Kh);
        hipLaunchKernelGGL((proj128<1>), dim3(512), dim3(256), 0, stream, Xv, WTv, bv, VTh);
    }
    hipLaunchKernelGGL(flash3, dim3(BB * HH * (SS / 128)), dim3(256), 0, stream,
                       Qh, Kh, VTh, mask, q, out);
}